// Round 8
// baseline (279.020 us; speedup 1.0000x reference)
//
#include <hip/hip_runtime.h>
#include <hip/hip_bf16.h>

typedef __bf16 bf16_t;
typedef __attribute__((ext_vector_type(8))) __bf16 bf16x8;
typedef __attribute__((ext_vector_type(4))) float f32x4;

#define DIM 2048
#define LAT 32
#define EPSF 1e-6f

__device__ __forceinline__ float gelu_f(float x) {
    return 0.5f * x * (1.0f + erff(x * 0.7071067811865475f));
}

// Pack We1 (2048x32 f32) and Wd2 (32x2048 f32) into bf16 MFMA B-fragment layout
// for mfma_f32_16x16x32_bf16 (identical to R0 — verified).
__global__ void pack_weights(const float* __restrict__ We1,
                             const float* __restrict__ Wd2,
                             bf16_t* __restrict__ We1p,
                             bf16_t* __restrict__ Wd2p) {
    int tid = blockIdx.x * 256 + threadIdx.x;  // 0..16383
    if (tid < 8192) {
        int l  = tid & 63;
        int nt = (tid >> 6) & 1;
        int t  = tid >> 7;
        int kg = l >> 4, mm = l & 15;
        int k0 = t * 32 + kg * 8;
        int n  = nt * 16 + mm;
        bf16_t* dst = We1p + (size_t)tid * 8;
#pragma unroll
        for (int i = 0; i < 8; ++i)
            dst[i] = (bf16_t)We1[(size_t)(k0 + i) * LAT + n];
    } else {
        int id = tid - 8192;
        int l  = id & 63;
        int nt = id >> 6;
        int kg = l >> 4, mm = l & 15;
        int n  = nt * 16 + mm;
        bf16_t* dst = Wd2p + (size_t)id * 8;
#pragma unroll
        for (int i = 0; i < 8; ++i)
            dst[i] = (bf16_t)Wd2[(size_t)(kg * 8 + i) * DIM + n];
    }
}

// ============ Kernel A (v2): encode(z0), encode(z1), slerp, decode-1 =========
// Rebuilt in decode_store's image: 2048 blocks x 4 waves, block = 16 rows,
// wave kq owns K-quarter [kq*512, +512) of BOTH z sources. Plain per-lane
// f32x4 loads in A-fragment layout (R0-proven), no gl_lds, no asm waits,
// compiler-scheduled. LDS 29 KB -> 4 blocks/CU -> 16 waves/CU.
// K-partials reduced via LDS; wave 0 runs slerp + decode-1, writes g-tile.
__global__ __launch_bounds__(256, 4)
void encode_slerp(const float* __restrict__ z0, const float* __restrict__ z1,
                  const float* __restrict__ tp,
                  const bf16x8* __restrict__ We1p,
                  const float* __restrict__ be1,
                  const float* __restrict__ We2,
                  const float* __restrict__ be2,
                  const float* __restrict__ Wd1,
                  const float* __restrict__ bd1,
                  bf16_t* __restrict__ gws) {
    const int tid  = threadIdx.x;
    const int kq   = tid >> 6;     // K-quarter
    const int lane = tid & 63;
    const int m16  = lane & 15;
    const int kg   = lane >> 4;
    const int rt   = blockIdx.x;   // 16-row tile index
    const int rowBase = rt * 16;
    const int phi  = ((int)blockIdx.x * 5) & 15;   // K-step rotation (channel spread)

    __shared__ float partial[4][4][64][4];   // 16 KB: [kq][acc j][lane][i]
    __shared__ float S0[16][33];             // 2.1 KB (reused as hm)
    __shared__ float S1[16][33];             // 2.1 KB
    __shared__ float W2[LAT * LAT];          // 4 KB
    __shared__ float W1s[LAT * LAT];         // 4 KB

    for (int i = tid; i < LAT * LAT; i += 256) {
        W2[i]  = We2[i];
        W1s[i] = Wd1[i];
    }
    const float tval = tp[0];

    // ---- Phase 1: partial S = z[rows, kq-quarter] @ We1[quarter]  (K=512)
    const float* zp0 = z0 + (size_t)(rowBase + m16) * DIM + kq * 512 + kg * 8;
    const float* zp1 = z1 + (size_t)(rowBase + m16) * DIM + kq * 512 + kg * 8;

    f32x4 acc00 = {0.f, 0.f, 0.f, 0.f};
    f32x4 acc01 = acc00, acc10 = acc00, acc11 = acc00;

#pragma unroll 2
    for (int t = 0; t < 16; ++t) {
        const int te = (t + phi) & 15;           // rotated K-step within quarter
        f32x4 a0lo = *(const f32x4*)(zp0 + te * 32);
        f32x4 a0hi = *(const f32x4*)(zp0 + te * 32 + 4);
        f32x4 a1lo = *(const f32x4*)(zp1 + te * 32);
        f32x4 a1hi = *(const f32x4*)(zp1 + te * 32 + 4);
        const int gk = kq * 16 + te;
        bf16x8 b0 = We1p[(gk * 2 + 0) * 64 + lane];
        bf16x8 b1 = We1p[(gk * 2 + 1) * 64 + lane];
        bf16x8 a0, a1;
#pragma unroll
        for (int i = 0; i < 4; ++i) {
            a0[i]     = (bf16_t)a0lo[i];
            a0[i + 4] = (bf16_t)a0hi[i];
            a1[i]     = (bf16_t)a1lo[i];
            a1[i + 4] = (bf16_t)a1hi[i];
        }
        acc00 = __builtin_amdgcn_mfma_f32_16x16x32_bf16(a0, b0, acc00, 0, 0, 0);
        acc01 = __builtin_amdgcn_mfma_f32_16x16x32_bf16(a0, b1, acc01, 0, 0, 0);
        acc10 = __builtin_amdgcn_mfma_f32_16x16x32_bf16(a1, b0, acc10, 0, 0, 0);
        acc11 = __builtin_amdgcn_mfma_f32_16x16x32_bf16(a1, b1, acc11, 0, 0, 0);
    }

    // ---- publish K-partials
    *(f32x4*)partial[kq][0][lane] = acc00;
    *(f32x4*)partial[kq][1][lane] = acc01;
    *(f32x4*)partial[kq][2][lane] = acc10;
    *(f32x4*)partial[kq][3][lane] = acc11;
    __syncthreads();

    if (kq != 0) return;   // waves 1-3 done; wave 0 finishes the tile

    // ---- K-reduce (wave 0 holds its own partials in acc**)
#pragma unroll
    for (int q = 1; q < 4; ++q) {
        f32x4 p0 = *(const f32x4*)partial[q][0][lane];
        f32x4 p1 = *(const f32x4*)partial[q][1][lane];
        f32x4 p2 = *(const f32x4*)partial[q][2][lane];
        f32x4 p3 = *(const f32x4*)partial[q][3][lane];
#pragma unroll
        for (int i = 0; i < 4; ++i) {
            acc00[i] += p0[i]; acc01[i] += p1[i];
            acc10[i] += p2[i]; acc11[i] += p3[i];
        }
    }

    // bias + exact GELU -> S tiles (D-layout: col = m16 / 16+m16, row = kg*4+i)
    {
        float be1a = be1[m16], be1b = be1[16 + m16];
#pragma unroll
        for (int i = 0; i < 4; ++i) {
            int row = kg * 4 + i;
            S0[row][m16]      = gelu_f(acc00[i] + be1a);
            S0[row][16 + m16] = gelu_f(acc01[i] + be1b);
            S1[row][m16]      = gelu_f(acc10[i] + be1a);
            S1[row][16 + m16] = gelu_f(acc11[i] + be1b);
        }
    }

    // ---- Phase 2 (wave-local): encode-2 + slerp; row = m16, j-chunk = kg*8..+7
    const int jb = kg * 8;
    {
        float h0v[8], h1v[8];
#pragma unroll
        for (int j = 0; j < 8; ++j) { h0v[j] = be2[jb + j]; h1v[j] = h0v[j]; }
        for (int k = 0; k < 32; ++k) {
            float a0k = S0[m16][k];
            float a1k = S1[m16][k];
#pragma unroll
            for (int j = 0; j < 8; ++j) {
                float w = W2[k * 32 + jb + j];
                h0v[j] += a0k * w;
                h1v[j] += a1k * w;
            }
        }
        float ss0 = 0.f, ss1 = 0.f;
#pragma unroll
        for (int j = 0; j < 8; ++j) { ss0 += h0v[j] * h0v[j]; ss1 += h1v[j] * h1v[j]; }
        ss0 += __shfl_xor(ss0, 16); ss0 += __shfl_xor(ss0, 32);
        ss1 += __shfl_xor(ss1, 16); ss1 += __shfl_xor(ss1, 32);
        float n0 = sqrtf(ss0), n1 = sqrtf(ss1);
        float inv0 = 1.f / (n0 + EPSF), inv1 = 1.f / (n1 + EPSF);
        float dotp = 0.f;
#pragma unroll
        for (int j = 0; j < 8; ++j) dotp += (h0v[j] * inv0) * (h1v[j] * inv1);
        dotp += __shfl_xor(dotp, 16); dotp += __shfl_xor(dotp, 32);
        dotp = fminf(fmaxf(dotp, -1.f + EPSF), 1.f - EPSF);
        float theta   = acosf(dotp);
        float scale   = 0.5f * (n0 + n1);
        float inv_sin = 1.f / sinf(theta);
        // theta >= acos(1-1e-6) ~ 1.4e-3 > EPS: slerp branch always taken
        float c0 = sinf((1.f - tval) * theta) * inv_sin * scale * inv0;
        float c1 = sinf(tval * theta) * inv_sin * scale * inv1;
        // hm overwrites S0 rows (fully consumed above; wave-lockstep safe)
#pragma unroll
        for (int j = 0; j < 8; ++j)
            S0[m16][jb + j] = c0 * h0v[j] + c1 * h1v[j];
    }

    // ---- decode layer 1: g lands exactly in A-fragment layout
    bf16x8 afrag;
    {
        float gv[8];
#pragma unroll
        for (int j = 0; j < 8; ++j) gv[j] = bd1[jb + j];
        for (int k = 0; k < 32; ++k) {
            float hk = S0[m16][k];
#pragma unroll
            for (int j = 0; j < 8; ++j)
                gv[j] += hk * W1s[k * 32 + jb + j];
        }
#pragma unroll
        for (int j = 0; j < 8; ++j) afrag[j] = (bf16_t)gelu_f(gv[j]);
    }

    // ---- write g-fragment: 1 KB contiguous per 16-row tile
    *(bf16x8*)(gws + (size_t)rt * 512 + lane * 8) = afrag;
}

// ============ Kernel B: out = g @ Wd2 + bd2 (streaming store) — unchanged ====
// 2048 blocks x 4 waves, 4 blocks/CU -> 16 waves/CU. Block = 16 output rows;
// wave wq owns cols [wq*512, +512). Swapped-operand MFMA (D: row=m16,
// cols=nt*16+kg*4+i) -> per-wave LDS slab (pitch 528) -> contiguous
// 512B-per-row dwordx4 stores.
__global__ __launch_bounds__(256, 4)
void decode_store(const bf16_t* __restrict__ gws,
                  const bf16x8* __restrict__ Wd2p,
                  const float* __restrict__ bd2,
                  float* __restrict__ out) {
    const int tid  = threadIdx.x;
    const int wq   = tid >> 6;     // col quarter
    const int lane = tid & 63;
    const int m16  = lane & 15;
    const int kg   = lane >> 4;
    const int rt   = blockIdx.x;   // 16-row tile index
    const int q    = lane & 31;
    const int rsel = lane >> 5;

    __shared__ __align__(16) unsigned char slabs[4][8448];
    char* slab = (char*)slabs[wq];

    const bf16x8 afrag = *(const bf16x8*)(gws + (size_t)rt * 512 + lane * 8);

    for (int cg = 0; cg < 4; ++cg) {
        const int c = wq * 4 + cg;           // 128-col group, 0..15
#pragma unroll
        for (int j = 0; j < 8; ++j) {
            int nt = c * 8 + j;
            bf16x8 bfrag = Wd2p[nt * 64 + lane];
            f32x4 d = {0.f, 0.f, 0.f, 0.f};
            d = __builtin_amdgcn_mfma_f32_16x16x32_bf16(bfrag, afrag, d, 0, 0, 0);
            *(f32x4*)(slab + (size_t)m16 * 528 + j * 64 + kg * 16) = d;
        }
        f32x4 bv = *(const f32x4*)(bd2 + c * 128 + q * 4);
#pragma unroll
        for (int r = 0; r < 8; ++r) {
            int row2 = r * 2 + rsel;
            f32x4 v = *(const f32x4*)(slab + (size_t)row2 * 528 + q * 16);
            f32x4 o;
#pragma unroll
            for (int i = 0; i < 4; ++i) o[i] = v[i] + bv[i];
            *(f32x4*)(out + (size_t)(rt * 16 + row2) * DIM + c * 128 + q * 4) = o;
        }
    }
}

extern "C" void kernel_launch(void* const* d_in, const int* in_sizes, int n_in,
                              void* d_out, int out_size, void* d_ws, size_t ws_size,
                              hipStream_t stream) {
    const float* z0  = (const float*)d_in[0];
    const float* z1  = (const float*)d_in[1];
    const float* tp  = (const float*)d_in[2];
    const float* We1 = (const float*)d_in[3];
    const float* be1 = (const float*)d_in[4];
    const float* We2 = (const float*)d_in[5];
    const float* be2 = (const float*)d_in[6];
    const float* Wd1 = (const float*)d_in[7];
    const float* bd1 = (const float*)d_in[8];
    const float* Wd2 = (const float*)d_in[9];
    const float* bd2 = (const float*)d_in[10];
    float* out = (float*)d_out;

    bf16_t* We1p = (bf16_t*)d_ws;                          // 65536 bf16 = 128 KB
    bf16_t* Wd2p = (bf16_t*)((char*)d_ws + 65536 * 2);     // 65536 bf16 = 128 KB
    bf16_t* gws  = (bf16_t*)((char*)d_ws + 65536 * 4);     // 1 M bf16  = 2 MB

    hipLaunchKernelGGL(pack_weights, dim3(64), dim3(256), 0, stream,
                       We1, Wd2, We1p, Wd2p);
    hipLaunchKernelGGL(encode_slerp, dim3(2048), dim3(256), 0, stream,
                       z0, z1, tp, (const bf16x8*)We1p, be1, We2, be2,
                       Wd1, bd1, gws);
    hipLaunchKernelGGL(decode_store, dim3(2048), dim3(256), 0, stream,
                       gws, (const bf16x8*)Wd2p, bd2, out);
}

// Round 9
// 134.712 us; speedup vs baseline: 2.0712x; 2.0712x over previous
//
#include <hip/hip_runtime.h>
#include <hip/hip_bf16.h>

typedef __bf16 bf16_t;
typedef __attribute__((ext_vector_type(8))) __bf16 bf16x8;
typedef __attribute__((ext_vector_type(4))) float f32x4;

#define DIM 2048
#define LAT 32
#define EPSF 1e-6f

__device__ __forceinline__ float gelu_f(float x) {
    return 0.5f * x * (1.0f + erff(x * 0.7071067811865475f));
}

// z staging: NON-TEMPORAL (aux=2 = NT cpol bit on gfx940+) — z has zero reuse;
// stop L2/L3 from retaining it (hypothesis: L3-hit service is SLOWER than HBM
// stream for this pattern, so retention across replays caps read rate).
__device__ __forceinline__ void gl_lds16_nt(const void* g, void* l) {
    __builtin_amdgcn_global_load_lds(
        (const __attribute__((address_space(1))) unsigned int*)g,
        (__attribute__((address_space(3))) unsigned int*)l, 16, 0, 2 /*NT*/);
}

// Pack We1 (2048x32 f32) and Wd2 (32x2048 f32) into bf16 MFMA B-fragment layout
// for mfma_f32_16x16x32_bf16 (identical to R0 — verified).
__global__ void pack_weights(const float* __restrict__ We1,
                             const float* __restrict__ Wd2,
                             bf16_t* __restrict__ We1p,
                             bf16_t* __restrict__ Wd2p) {
    int tid = blockIdx.x * 256 + threadIdx.x;  // 0..16383
    if (tid < 8192) {
        int l  = tid & 63;
        int nt = (tid >> 6) & 1;
        int t  = tid >> 7;
        int kg = l >> 4, mm = l & 15;
        int k0 = t * 32 + kg * 8;
        int n  = nt * 16 + mm;
        bf16_t* dst = We1p + (size_t)tid * 8;
#pragma unroll
        for (int i = 0; i < 8; ++i)
            dst[i] = (bf16_t)We1[(size_t)(k0 + i) * LAT + n];
    } else {
        int id = tid - 8192;
        int l  = id & 63;
        int nt = id >> 6;
        int kg = l >> 4, mm = l & 15;
        int n  = nt * 16 + mm;
        bf16_t* dst = Wd2p + (size_t)id * 8;
#pragma unroll
        for (int i = 0; i < 8; ++i)
            dst[i] = (bf16_t)Wd2[(size_t)(kg * 8 + i) * DIM + n];
    }
}

// R5 kernel, byte-identical access patterns; ONLY cache-policy changes:
//  - z gl_lds loads are non-temporal (aux=2)
//  - final out stores are non-temporal
__global__ __launch_bounds__(256, 2)
void fused_manifold(const float* __restrict__ z0, const float* __restrict__ z1,
                    const float* __restrict__ tp,
                    const bf16x8* __restrict__ We1p,
                    const float* __restrict__ be1,
                    const float* __restrict__ We2,
                    const float* __restrict__ be2,
                    const float* __restrict__ We2_unused,
                    const float* __restrict__ Wd1,
                    const float* __restrict__ bd1,
                    const bf16x8* __restrict__ Wd2p,
                    const float* __restrict__ bd2,
                    float* __restrict__ out) {
    const int tid  = threadIdx.x;
    const int wave = tid >> 6;
    const int lane = tid & 63;
    const int m16  = lane & 15;
    const int kg   = lane >> 4;
    const int blockRow = blockIdx.x * 64;
    const int waveRow  = blockRow + wave * 16;
    const int phi  = ((int)blockIdx.x * 5 + wave * 4) & 15;

    // LDS map (total 81152 B -> 2 blocks/CU):
    //  [0, 66560)       stage: wave slice 16640 = z0: 8 pairs x 1040, z1: +8320
    //                   (reused after phase 2 as the phase-3 out slab, pitch 528)
    //  [66560, 75008)   S bf16 [2][64][33] (src0/src1 gelu tiles; src0 reused as hm)
    //  [75008, 79104)   We2s f32 [32][32]
    //  [79104, 81152)   Wd1s bf16 [32][32]
    __shared__ __align__(16) unsigned char lds[81152];
    bf16_t* S  = (bf16_t*)(lds + 66560);
    float*  W2 = (float*) (lds + 75008);
    bf16_t* W1 = (bf16_t*)(lds + 79104);
    char*   stw = (char*)lds + wave * 16640;

    for (int i = tid; i < LAT * LAT; i += 256) {
        W2[i] = We2[i];
        W1[i] = (bf16_t)Wd1[i];
    }
    const float tval = tp[0];
    __syncthreads();   // W2/W1 visible to all waves

    // ---- Phase 1: S = z_tile @ We1 (16 rows/wave, N=32, K=2048), both sources.
    const char* z0src = (const char*)z0 + (size_t)(waveRow + (lane >> 5)) * (DIM * 4) + (lane & 31) * 16;
    const char* z1src = (const char*)z1 + (size_t)(waveRow + (lane >> 5)) * (DIM * 4) + (lane & 31) * 16;

#define STG(srcp, dstoff, kbv)                                             \
    {                                                                      \
        _Pragma("unroll")                                                  \
        for (int i_ = 0; i_ < 8; ++i_)                                     \
            gl_lds16_nt(srcp + (size_t)i_ * 16384 + (kbv) * 512,           \
                        stw + (dstoff) + i_ * 1040);                       \
    }

    f32x4 acc00 = {0.f, 0.f, 0.f, 0.f};
    f32x4 acc01 = acc00, acc10 = acc00, acc11 = acc00;
    const char* abase0 = stw + (m16 >> 1) * 1040 + (m16 & 1) * 512 + kg * 32;
    const char* abase1 = abase0 + 8320;

    STG(z0src, 0, phi);                                 // vmcnt: 8 outstanding

#pragma unroll 1
    for (int ss = 0; ss < 16; ++ss) {
        const int kb  = (ss + phi) & 15;
        const int kbn = (ss + 1 + phi) & 15;
        bf16x8 Bf0[4], Bf1[4];
#pragma unroll
        for (int k = 0; k < 4; ++k) {
            int gk = kb * 4 + k;
            Bf0[k] = We1p[(gk * 2 + 0) * 64 + lane];
            Bf1[k] = We1p[(gk * 2 + 1) * 64 + lane];
        }
        __builtin_amdgcn_sched_barrier(0);
        STG(z1src, 8320, kb);                           // outstanding: 8 z0 + 8 B + 8 z1
        asm volatile("s_waitcnt vmcnt(16)" ::: "memory");  // z0(kb) LDS ready
#pragma unroll
        for (int k = 0; k < 4; ++k) {
            f32x4 lo = *(const f32x4*)(abase0 + k * 128);
            f32x4 hi = *(const f32x4*)(abase0 + k * 128 + 16);
            bf16x8 a;
#pragma unroll
            for (int i = 0; i < 4; ++i) { a[i] = (bf16_t)lo[i]; a[i + 4] = (bf16_t)hi[i]; }
            acc00 = __builtin_amdgcn_mfma_f32_16x16x32_bf16(a, Bf0[k], acc00, 0, 0, 0);
            acc01 = __builtin_amdgcn_mfma_f32_16x16x32_bf16(a, Bf1[k], acc01, 0, 0, 0);
        }
        asm volatile("s_waitcnt lgkmcnt(0)" ::: "memory");   // z0 buffer reads retired
        __builtin_amdgcn_sched_barrier(0);
        if (ss < 15) {
            STG(z0src, 0, kbn);
            asm volatile("s_waitcnt vmcnt(8)" ::: "memory"); // z1(kb) ready
        } else {
            asm volatile("s_waitcnt vmcnt(0)" ::: "memory");
        }
#pragma unroll
        for (int k = 0; k < 4; ++k) {
            f32x4 lo = *(const f32x4*)(abase1 + k * 128);
            f32x4 hi = *(const f32x4*)(abase1 + k * 128 + 16);
            bf16x8 a;
#pragma unroll
            for (int i = 0; i < 4; ++i) { a[i] = (bf16_t)lo[i]; a[i + 4] = (bf16_t)hi[i]; }
            acc10 = __builtin_amdgcn_mfma_f32_16x16x32_bf16(a, Bf0[k], acc10, 0, 0, 0);
            acc11 = __builtin_amdgcn_mfma_f32_16x16x32_bf16(a, Bf1[k], acc11, 0, 0, 0);
        }
        asm volatile("s_waitcnt lgkmcnt(0)" ::: "memory");   // z1 buffer reads retired
        __builtin_amdgcn_sched_barrier(0);
    }
#undef STG

    // ---- bias + exact GELU -> S tiles (bf16), D-layout col=m16, rows kg*4+i.
    {
        float be1a = be1[m16], be1b = be1[16 + m16];
#pragma unroll
        for (int i = 0; i < 4; ++i) {
            int row = wave * 16 + kg * 4 + i;
            S[row * 33 + m16]               = (bf16_t)gelu_f(acc00[i] + be1a);
            S[row * 33 + 16 + m16]          = (bf16_t)gelu_f(acc01[i] + be1b);
            S[2112 + row * 33 + m16]        = (bf16_t)gelu_f(acc10[i] + be1a);
            S[2112 + row * 33 + 16 + m16]   = (bf16_t)gelu_f(acc11[i] + be1b);
        }
    }

    // ---- Phase 2 (wave-local): encode-2 + slerp; row = m16, j-chunk = kg*8..+7
    const int jb = kg * 8;
    {
        const int row = wave * 16 + m16;
        float h0v[8], h1v[8];
#pragma unroll
        for (int j = 0; j < 8; ++j) { h0v[j] = be2[jb + j]; h1v[j] = h0v[j]; }
        for (int k = 0; k < 32; ++k) {
            float a0k = (float)S[row * 33 + k];
            float a1k = (float)S[2112 + row * 33 + k];
#pragma unroll
            for (int j = 0; j < 8; ++j) {
                float w = W2[k * 32 + jb + j];
                h0v[j] += a0k * w;
                h1v[j] += a1k * w;
            }
        }
        float ss0 = 0.f, ss1 = 0.f;
#pragma unroll
        for (int j = 0; j < 8; ++j) { ss0 += h0v[j] * h0v[j]; ss1 += h1v[j] * h1v[j]; }
        ss0 += __shfl_xor(ss0, 16); ss0 += __shfl_xor(ss0, 32);
        ss1 += __shfl_xor(ss1, 16); ss1 += __shfl_xor(ss1, 32);
        float n0 = sqrtf(ss0), n1 = sqrtf(ss1);
        float inv0 = 1.f / (n0 + EPSF), inv1 = 1.f / (n1 + EPSF);
        float dotp = 0.f;
#pragma unroll
        for (int j = 0; j < 8; ++j) dotp += (h0v[j] * inv0) * (h1v[j] * inv1);
        dotp += __shfl_xor(dotp, 16); dotp += __shfl_xor(dotp, 32);
        dotp = fminf(fmaxf(dotp, -1.f + EPSF), 1.f - EPSF);
        float theta   = acosf(dotp);
        float scale   = 0.5f * (n0 + n1);
        float inv_sin = 1.f / sinf(theta);
        // theta >= acos(1-1e-6) ~ 1.4e-3 > EPS: slerp branch always taken
        float c0 = sinf((1.f - tval) * theta) * inv_sin * scale * inv0;
        float c1 = sinf(tval * theta) * inv_sin * scale * inv1;
        // hm overwrites S src0 slice (fully consumed above; wave-lockstep safe)
#pragma unroll
        for (int j = 0; j < 8; ++j)
            S[row * 33 + jb + j] = (bf16_t)(c0 * h0v[j] + c1 * h1v[j]);
    }

    // ---- decode layer 1 (wave-local): g lands exactly in A-fragment layout
    bf16x8 afrag;
    {
        const int row = wave * 16 + m16;
        float gv[8];
#pragma unroll
        for (int j = 0; j < 8; ++j) gv[j] = bd1[jb + j];
        for (int k = 0; k < 32; ++k) {
            float hk = (float)S[row * 33 + k];
#pragma unroll
            for (int j = 0; j < 8; ++j)
                gv[j] += hk * (float)W1[k * 32 + jb + j];
        }
#pragma unroll
        for (int j = 0; j < 8; ++j) afrag[j] = (bf16_t)gelu_f(gv[j]);
    }

    // All waves done with the stage region before it becomes the out slab.
    __syncthreads();

    // ---- Phase 3: out = g @ Wd2 + bd2, via swapped-operand MFMA (R1-verified
    // D-layout: row=m16, cols=nt*16+kg*4+i) -> LDS slab (pitch 528) ->
    // CONTIGUOUS 512B-per-row NON-TEMPORAL dwordx4 stores (out never re-read).
    {
        const int q    = lane & 31;
        const int rsel = lane >> 5;
        for (int ci = 0; ci < 16; ++ci) {
            const int c = (ci + phi) & 15;
#pragma unroll
            for (int j = 0; j < 8; ++j) {
                int nt = c * 8 + j;
                bf16x8 bfrag = Wd2p[nt * 64 + lane];
                f32x4 d = {0.f, 0.f, 0.f, 0.f};
                d = __builtin_amdgcn_mfma_f32_16x16x32_bf16(bfrag, afrag, d, 0, 0, 0);
                *(f32x4*)((char*)lds + (size_t)(wave * 16 + m16) * 528 + j * 64 + kg * 16) = d;
            }
            f32x4 bv = *(const f32x4*)(bd2 + c * 128 + q * 4);
#pragma unroll
            for (int r = 0; r < 8; ++r) {
                int row2 = r * 2 + rsel;
                f32x4 v = *(const f32x4*)((char*)lds + (size_t)(wave * 16 + row2) * 528 + q * 16);
                f32x4 o;
#pragma unroll
                for (int i = 0; i < 4; ++i) o[i] = v[i] + bv[i];
                __builtin_nontemporal_store(
                    o, (f32x4*)(out + (size_t)(blockRow + wave * 16 + row2) * DIM + c * 128 + q * 4));
            }
        }
    }
}

extern "C" void kernel_launch(void* const* d_in, const int* in_sizes, int n_in,
                              void* d_out, int out_size, void* d_ws, size_t ws_size,
                              hipStream_t stream) {
    const float* z0  = (const float*)d_in[0];
    const float* z1  = (const float*)d_in[1];
    const float* tp  = (const float*)d_in[2];
    const float* We1 = (const float*)d_in[3];
    const float* be1 = (const float*)d_in[4];
    const float* We2 = (const float*)d_in[5];
    const float* be2 = (const float*)d_in[6];
    const float* Wd1 = (const float*)d_in[7];
    const float* bd1 = (const float*)d_in[8];
    const float* Wd2 = (const float*)d_in[9];
    const float* bd2 = (const float*)d_in[10];
    float* out = (float*)d_out;

    bf16_t* We1p = (bf16_t*)d_ws;                         // 65536 bf16 = 128 KB
    bf16_t* Wd2p = (bf16_t*)((char*)d_ws + 65536 * 2);    // 65536 bf16 = 128 KB

    hipLaunchKernelGGL(pack_weights, dim3(64), dim3(256), 0, stream,
                       We1, Wd2, We1p, Wd2p);
    hipLaunchKernelGGL(fused_manifold, dim3(512), dim3(256), 0, stream,
                       z0, z1, tp, (const bf16x8*)We1p, be1, We2, be2,
                       We2, Wd1, bd1, (const bf16x8*)Wd2p, bd2, out);
}